// Round 1
// baseline (537.625 us; speedup 1.0000x reference)
//
#include <hip/hip_runtime.h>

#define V      4096
#define S_DIM  256
#define B_DIM  64
#define ALPHA_W  0.4f
#define BETA_W   0.3f
#define UNI_W    0.3f        // 1 - ALPHA - BETA
#define EPS_F    1e-10f

constexpr int THREADS = 256;
constexpr int VEC_PER_THREAD = V / (4 * THREADS);  // 4 float4 chunks per thread

__global__ __launch_bounds__(THREADS)
void ngram_logprob_kernel(const int*   __restrict__ text,
                          const float* __restrict__ unigram,
                          const float* __restrict__ bigram,
                          const float* __restrict__ tri_rows,
                          const int*   __restrict__ tri_map,
                          float*       __restrict__ out)
{
    const int sb = blockIdx.x;          // sb = s * B_DIM + b  (matches output layout)
    const int s  = sb >> 6;             // B_DIM = 64
    const int t  = threadIdx.x;

    // ---- wave-uniform scalar setup -------------------------------------
    const int cur = text[sb];
    float tw = 0.0f;                    // trigram weight (0 when context absent)
    long  trig_row = 0;
    if (s > 1) {
        const int prev = text[sb - B_DIM];
        const int ridx = tri_map[prev * V + cur];
        if (ridx >= 0) { tw = BETA_W; trig_row = (long)ridx; }
    }

    const float4* __restrict__ uni4 = (const float4*)unigram;
    const float4* __restrict__ bi4  = (const float4*)(bigram + (size_t)cur * V);
    const float4* __restrict__ tr4  = (const float4*)(tri_rows + (size_t)trig_row * V);

    // ---- pass 1: weighted mix into registers + local sum ---------------
    float4 p[VEC_PER_THREAD];
    float  lsum = 0.0f;
    #pragma unroll
    for (int k = 0; k < VEC_PER_THREAD; ++k) {
        const int c = t + k * THREADS;              // coalesced: lane i -> chunk i
        const float4 u  = uni4[c];
        const float4 bb = bi4[c];
        const float4 tv = tr4[c];   // row 0 (L1-hot) when tw==0 — branch-free
        float4 pv;
        pv.x = fmaf(tw, tv.x, fmaf(ALPHA_W, bb.x, UNI_W * u.x));
        pv.y = fmaf(tw, tv.y, fmaf(ALPHA_W, bb.y, UNI_W * u.y));
        pv.z = fmaf(tw, tv.z, fmaf(ALPHA_W, bb.z, UNI_W * u.z));
        pv.w = fmaf(tw, tv.w, fmaf(ALPHA_W, bb.w, UNI_W * u.w));
        p[k] = pv;
        lsum += (pv.x + pv.y) + (pv.z + pv.w);
    }

    // ---- block reduction: wave64 shuffle, then LDS across 4 waves ------
    #pragma unroll
    for (int off = 32; off > 0; off >>= 1)
        lsum += __shfl_down(lsum, off, 64);

    __shared__ float wsum[THREADS / 64];
    const int wave = t >> 6;
    if ((t & 63) == 0) wsum[wave] = lsum;
    __syncthreads();

    float total = 0.0f;
    #pragma unroll
    for (int w = 0; w < THREADS / 64; ++w) total += wsum[w];  // broadcast reads

    const float inv = 1.0f / (EPS_F + total);

    // ---- pass 2: normalize + log + coalesced float4 store --------------
    float4* __restrict__ o4 = (float4*)(out + (size_t)sb * V);
    #pragma unroll
    for (int k = 0; k < VEC_PER_THREAD; ++k) {
        const int c = t + k * THREADS;
        const float4 pv = p[k];
        float4 ov;
        ov.x = __logf(EPS_F + pv.x * inv);
        ov.y = __logf(EPS_F + pv.y * inv);
        ov.z = __logf(EPS_F + pv.z * inv);
        ov.w = __logf(EPS_F + pv.w * inv);
        o4[c] = ov;
    }
}

extern "C" void kernel_launch(void* const* d_in, const int* in_sizes, int n_in,
                              void* d_out, int out_size, void* d_ws, size_t ws_size,
                              hipStream_t stream)
{
    const int*   text     = (const int*)  d_in[0];
    const float* unigram  = (const float*)d_in[1];
    const float* bigram   = (const float*)d_in[2];
    const float* tri_rows = (const float*)d_in[3];
    const int*   tri_map  = (const int*)  d_in[4];
    float*       out      = (float*)      d_out;

    ngram_logprob_kernel<<<dim3(S_DIM * B_DIM), dim3(THREADS), 0, stream>>>(
        text, unigram, bigram, tri_rows, tri_map, out);
}